// Round 5
// baseline (580.825 us; speedup 1.0000x reference)
//
#include <hip/hip_runtime.h>
#include <hip/hip_bf16.h>
#include <math.h>

typedef unsigned short u16;
typedef __attribute__((ext_vector_type(8))) short s16x8;   // 8 bf16 (4 VGPRs)
typedef __attribute__((ext_vector_type(4))) float f32x4;   // MFMA 16x16 accumulator

#define NB_ 256
#define L_  64
#define KK_ 65
#define C_  512
#define H_  8
#define NEDGE (256*64*65)             // 1,064,960
#define MTOT  65536                   // total rows = B * NB * L

__device__ __forceinline__ float b2f(u16 u){
  union { unsigned int i; float f; } x; x.i = ((unsigned int)u) << 16; return x.f;
}
__device__ __forceinline__ u16 f2b(float f){
  union { float f; unsigned int i; } x; x.f = f;
  return (u16)((x.i + 0x7FFFu + ((x.i >> 16) & 1u)) >> 16);  // RNE
}

// async global->LDS, 16B per lane. LDS dest: wave-uniform base + lane*16.
__device__ __forceinline__ void gload_lds16(const u16* g, u16* l){
  __builtin_amdgcn_global_load_lds(
      (const __attribute__((address_space(1))) unsigned int*)g,
      (__attribute__((address_space(3))) unsigned int*)l,
      16, 0, 0);
}

// ---------------------------------------------------------------------------
// Input dtype detector. flagdt: 1 = f32 inputs, 0 = bf16.
// ---------------------------------------------------------------------------
__global__ void detect_dtype_kernel(const u16* __restrict__ x, int* __restrict__ flagdt){
  __shared__ int cnt;
  if (threadIdx.x == 0) cnt = 0;
  __syncthreads();
  u16 v = x[(size_t)threadIdx.x * 2 * 1001];   // even indices, spread out
  int e = (v >> 7) & 0xFF;                     // bf16 exponent field
  if (e >= 141) atomicAdd(&cnt, 1);            // |v| >= 2^14 or NaN/Inf
  __syncthreads();
  if (threadIdx.x == 0) *flagdt = (cnt >= 8) ? 1 : 0;
}

// ---------------------------------------------------------------------------
// Mask dtype detector: attn_mask[:, :, 64] is always True under the true
// element width; wrong widths read random data and fail w.p. ~1.
// ---------------------------------------------------------------------------
__global__ void detect_mask_kernel(const unsigned char* __restrict__ m, int* __restrict__ flag){
  __shared__ int ok1, ok2, ok4;
  if (threadIdx.x == 0){ ok1 = 1; ok2 = 1; ok4 = 1; }
  __syncthreads();
  size_t e = (size_t)threadIdx.x * 65 + 64;   // rows 0..127 (n=0,1), col 64
  if (((const unsigned char*)m)[e] == 0)  atomicAnd(&ok1, 0);
  if (((const unsigned short*)m)[e] == 0) atomicAnd(&ok2, 0);
  if (((const unsigned int*)m)[e] == 0u)  atomicAnd(&ok4, 0);
  __syncthreads();
  if (threadIdx.x == 0){
    int f = 4;
    if (ok2) f = 2;
    if (ok1) f = 1;
    *flag = f;
  }
}

// ---------------------------------------------------------------------------
// Canonicalize a float tensor to bf16 (n must be a multiple of 8)
// ---------------------------------------------------------------------------
__global__ void convert_kernel(const void* __restrict__ src, u16* __restrict__ dst,
                               long n, const int* __restrict__ flagdt){
  long i = ((long)blockIdx.x * 256 + threadIdx.x) * 8;
  if (i >= n) return;
  if (*flagdt){
    const float* s = (const float*)src + i;
    u16 o[8];
    #pragma unroll
    for (int j = 0; j < 8; ++j) o[j] = f2b(s[j]);
    *(s16x8*)(dst + i) = *(const s16x8*)o;
  } else {
    *(s16x8*)(dst + i) = *(const s16x8*)((const u16*)src + i);
  }
}

// ---------------------------------------------------------------------------
// Fused score-bias precompute: dst[i] for i = (nb*64 + l)*65 + kk:
//   !mask          -> -1e9
//   kk==64 || kk==l -> 1.0
//   else            -> edge_feats[i][3]
// ---------------------------------------------------------------------------
__global__ void build_bias_kernel(const void* __restrict__ edge,
                                  const unsigned char* __restrict__ mask,
                                  const int* __restrict__ flagdt,
                                  const int* __restrict__ flagm,
                                  u16* __restrict__ dst){
  long i = (long)blockIdx.x * 256 + threadIdx.x;
  if (i >= NEDGE) return;
  int kk = (int)(i % 65);
  long rowi = i / 65;                 // nb*64 + l
  int l = (int)(rowi & 63);
  int fm = *flagm;
  bool mt;
  if (fm == 1)      mt = mask[i] != 0;
  else if (fm == 2) mt = ((const unsigned short*)mask)[i] != 0;
  else              mt = ((const unsigned int*)mask)[i]   != 0u;
  float v;
  if (!mt)                      v = -1e9f;
  else if (kk == 64 || kk == l) v = 1.0f;
  else v = (*flagdt) ? ((const float*)edge)[i*4 + 3] : b2f(((const u16*)edge)[i*4 + 3]);
  dst[i] = f2b(v);
}

// transpose + canonicalize weight matrices (small)
__global__ void transpose_conv_kernel(const void* __restrict__ in, u16* __restrict__ out,
                                      int R, int Cc, const int* __restrict__ flagdt){
  long i = (long)blockIdx.x * 256 + threadIdx.x;
  if (i < (long)R * Cc){
    int r = (int)(i / Cc), c = (int)(i % Cc);
    u16 v = (*flagdt) ? f2b(((const float*)in)[i]) : ((const u16*)in)[i];
    out[(long)c * R + r] = v;
  }
}

// ---------------------------------------------------------------------------
// Per-block mean over L=64 rows -> BM[1024][512]   (reads canonical bf16 X)
// ---------------------------------------------------------------------------
__global__ __launch_bounds__(256) void block_mean_kernel(const u16* __restrict__ x, u16* __restrict__ bm){
  int blk = blockIdx.x;
  const u16* xp = x + (long)blk * 64 * 512;
  for (int c = threadIdx.x; c < 512; c += 256){
    float s = 0.f;
    #pragma unroll
    for (int l = 0; l < 64; ++l) s += b2f(xp[l*512 + c]);
    bm[(long)blk * 512 + c] = f2b(s * 0.015625f);
  }
}

// ---------------------------------------------------------------------------
// GEMM: C[M,N] = A[M,K] @ BT[N,K]^T + bias[n]
// 128x128 tile, BK=32, 4 waves, 16x16x32 bf16 MFMA.
// 2-PHASE PIPELINE (T3/T4 minimum): double-buffered LDS K-tiles; the next
// tile's global_load_lds are issued BEFORE computing the current tile, and
// the barrier uses raw s_barrier + counted s_waitcnt vmcnt(4) so the 4
// newest loads stay in flight across the barrier (no vmcnt(0) drain in the
// main loop). Buffer b staged at phase p is re-staged only at p+2; the
// end-of-phase barrier orders all waves' ds_reads before that.
// LDS 32 KB total (same occupancy as BK=64 single-buffer).
// Requires Kdim % 64 == 0 (all calls use K=512 -> 16 phases).
// out_mode=1: consult *flagdt; if set, write f32 at Cmat (cast) with the
// given row offset in ELEMENTS of the output dtype (row_off rows of ldc).
// ---------------------------------------------------------------------------
__global__ __launch_bounds__(256) void gemm_bt_kernel(
    const u16* __restrict__ A, const u16* __restrict__ BT,
    const u16* __restrict__ bias, u16* __restrict__ Cmat,
    int lda, int ldc, int Kdim, const int* __restrict__ flagdt, int out_mode,
    long row_off)
{
  __shared__ __align__(16) u16 As[2*128*32];   // buffers at elem 0 / 4096
  __shared__ __align__(16) u16 Bs[2*128*32];
  const int t = threadIdx.x;
  const int lane = t & 63;
  const int w = t >> 6;
  const int wm = w & 1, wn = w >> 1;
  const int quad = lane >> 4;
  const int ml = lane & 15;

  // XCD-aware bijective swizzle (all grids used have nwg % 8 == 0)
  const int nwg  = gridDim.x * gridDim.y;
  const int orig = blockIdx.y * gridDim.x + blockIdx.x;
  int lid = orig;
  if ((nwg & 7) == 0) lid = (orig & 7) * (nwg >> 3) + (orig >> 3);
  const int bx = lid % gridDim.x;
  const int by = lid / gridDim.x;
  const long colbase = (long)bx * 128;
  const long rowbase = (long)by * 128;
  const int of = out_mode ? *flagdt : 0;

  const f32x4 zero4 = {0.f, 0.f, 0.f, 0.f};
  f32x4 acc[4][4];
  #pragma unroll
  for (int i = 0; i < 4; ++i)
    #pragma unroll
    for (int j = 0; j < 4; ++j) acc[i][j] = zero4;

  // source-address swizzle: thread t's LDS slot byte offset is t*16 (batch0)
  // / 4096+t*16 (batch1); its global source is row r, 16B-chunk g = s ^ ((r>>1)&3).
  const int c0 = t,       r0 = c0 >> 2, s0 = c0 & 3, g0 = s0 ^ ((r0 >> 1) & 3);
  const int c1 = t + 256, r1 = c1 >> 2, s1 = c1 & 3, g1 = s1 ^ ((r1 >> 1) & 3);
  const u16* Arow0 = A + (rowbase + r0) * (long)lda + g0*8;
  const u16* Arow1 = A + (rowbase + r1) * (long)lda + g1*8;
  const u16* Brow0 = BT + (colbase + r0) * (long)Kdim + g0*8;
  const u16* Brow1 = BT + (colbase + r1) * (long)Kdim + g1*8;

  // stage K-tile (32 wide) at element offset k0 into buffer b (4 loads/thread)
  auto stage = [&](int b, int k0){
    gload_lds16(Arow0 + k0, As + b*4096 + w*512);
    gload_lds16(Arow1 + k0, As + b*4096 + 2048 + w*512);
    gload_lds16(Brow0 + k0, Bs + b*4096 + w*512);
    gload_lds16(Brow1 + k0, Bs + b*4096 + 2048 + w*512);
  };
  // compute one staged 32-wide K-tile from buffer b
  auto compute = [&](int b){
    const u16* Ab = As + b*4096;
    const u16* Bb = Bs + b*4096;
    s16x8 af[4], bfr[4];
    #pragma unroll
    for (int i = 0; i < 4; ++i){
      int m = wm*64 + i*16 + ml;
      af[i]  = *(const s16x8*)(Ab + m*32 + ((quad ^ ((m>>1)&3)))*8);
      int n = wn*64 + i*16 + ml;
      bfr[i] = *(const s16x8*)(Bb + n*32 + ((quad ^ ((n>>1)&3)))*8);
    }
    #pragma unroll
    for (int i = 0; i < 4; ++i)
      #pragma unroll
      for (int j = 0; j < 4; ++j)
        acc[i][j] = __builtin_amdgcn_mfma_f32_16x16x32_bf16(af[i], bfr[j], acc[i][j], 0, 0, 0);
  };

  const int nk = Kdim >> 5;                 // 16 for K=512 (even)
  stage(0, 0);                              // prologue: buf0 <- tile 0
  for (int kt = 0; kt < nk; kt += 2){
    // phase A: prefetch tile kt+1 into buf1, compute buf0 (tile kt)
    stage(1, (kt+1) << 5);                  // kt+1 <= nk-1 always (nk even)
    asm volatile("s_waitcnt vmcnt(4)" ::: "memory");   // buf0's 4 landed
    __builtin_amdgcn_s_barrier();
    compute(0);
    __builtin_amdgcn_s_barrier();           // all reads of buf0 done
    // phase B: prefetch tile kt+2 into buf0, compute buf1 (tile kt+1)
    int knxt = (kt+2 < nk) ? (kt+2) << 5 : (nk-1) << 5;  // clamp: unused restage
    stage(0, knxt);
    asm volatile("s_waitcnt vmcnt(4)" ::: "memory");   // buf1's 4 landed
    __builtin_amdgcn_s_barrier();
    compute(1);
    __builtin_amdgcn_s_barrier();           // all reads of buf1 done
  }

  // epilogue: C/D layout col=lane&15, row=quad*4+reg
  #pragma unroll
  for (int j = 0; j < 4; ++j){
    long col = colbase + wn*64 + j*16 + ml;
    float bv = b2f(bias[col]);
    #pragma unroll
    for (int i = 0; i < 4; ++i){
      long row = row_off + rowbase + wm*64 + i*16 + quad*4;
      if (of){
        float* Cf = (float*)Cmat;
        #pragma unroll
        for (int r = 0; r < 4; ++r)
          Cf[(row + r) * (long)ldc + col] = acc[i][j][r] + bv;
      } else {
        #pragma unroll
        for (int r = 0; r < 4; ++r)
          Cmat[(row + r) * (long)ldc + col] = f2b(acc[i][j][r] + bv);
      }
    }
  }
}

// ---------------------------------------------------------------------------
// Attention: one WG per (block, head-PAIR), grid 1024x4. Two heads run
// sequentially in one WG, reusing: LDS pad zero-fills, and the 20-reg
// head-independent score-bias block (loaded once). LDS 37.25 KB -> 4 WG/CU.
// ---------------------------------------------------------------------------
__global__ __launch_bounds__(256, 4) void attn_kernel(
    const u16* __restrict__ Y, const u16* __restrict__ kvb,
    const u16* __restrict__ biasb, u16* __restrict__ AO)
{
  __shared__ __align__(16) u16 k_s [80*72];
  __shared__ __align__(16) u16 vT_s[64*104];
  __shared__ __align__(16) u16 P_s [64*104];

  const int t = threadIdx.x;
  const int lane = t & 63;
  const int w = t >> 6;
  const int quad = lane >> 4;
  const int ml = lane & 15;

  // XCD swizzle: co-locate a block's 4 head-pairs on one XCD
  const int orig = blockIdx.y * gridDim.x + blockIdx.x;   // 0..4095
  const int lid  = (orig & 7) * 512 + (orig >> 3);
  const int blk  = lid >> 2;
  const int hp   = lid & 3;          // head pair: heads hp*2, hp*2+1
  const int nb = blk & (NB_ - 1);
  const long yrow0 = (long)blk * 64;

  // head-independent score bias -> registers (reused for both heads)
  float bb[5][4];
  #pragma unroll
  for (int j = 0; j < 5; ++j){
    int kk = j*16 + ml;
    #pragma unroll
    for (int r = 0; r < 4; ++r){
      int l = w*16 + quad*4 + r;
      bb[j][r] = (kk < 65) ? b2f(biasb[((long)nb*64 + l)*65 + kk]) : 0.f;
    }
  }

  // pad zero-fills (persist across both heads)
  for (int i = t; i < 64*31; i += 256){ int d = i/31, c = 65 + (i%31); vT_s[d*104 + c] = 0; }
  for (int i = t; i < 64*16; i += 256){ int l = i>>4,  c = 80 + (i&15); P_s[l*104 + c] = 0; }
  for (int i = t; i < 15*72; i += 256){ k_s[65*72 + i] = 0; }

  const f32x4 zero4 = {0.f, 0.f, 0.f, 0.f};

  for (int hh = 0; hh < 2; ++hh){
    const int h = hp*2 + hh;
    if (hh) __syncthreads();   // head0's ds_reads all precede this barrier

    // Q fragments straight to registers
    const u16* qrow = Y + (yrow0 + w*16 + ml)*1536 + h*64 + quad*8;
    s16x8 aq0 = *(const s16x8*)(qrow);
    s16x8 aq1 = *(const s16x8*)(qrow + 32);

    for (int c = t; c < 520; c += 256){
      int kk = c >> 3, c8 = c & 7;
      const u16 *srck, *srcv;
      if (kk < 64){
        const u16* base = Y + (yrow0 + kk)*1536;
        srck = base + 512  + h*64 + c8*8;
        srcv = base + 1024 + h*64 + c8*8;
      } else {
        const u16* base = kvb + (long)blk * 1024;
        srck = base + h*64 + c8*8;
        srcv = base + 512 + h*64 + c8*8;
      }
      *(s16x8*)(k_s + kk*72 + c8*8) = *(const s16x8*)srck;
      s16x8 vv = *(const s16x8*)srcv;
      #pragma unroll
      for (int j = 0; j < 8; ++j){
        int jj = (j + c8) & 7;          // bank-rotate scatter: 16-way -> 2-way
        vT_s[(c8*8 + jj)*104 + kk] = (u16)vv[jj];
      }
    }
    __syncthreads();

    f32x4 sacc[5];
    #pragma unroll
    for (int j = 0; j < 5; ++j) sacc[j] = zero4;
    #pragma unroll
    for (int j = 0; j < 5; ++j){
      s16x8 bk0 = *(const s16x8*)(k_s + (j*16 + ml)*72 + quad*8);
      sacc[j] = __builtin_amdgcn_mfma_f32_16x16x32_bf16(aq0, bk0, sacc[j], 0, 0, 0);
      s16x8 bk1 = *(const s16x8*)(k_s + (j*16 + ml)*72 + 32 + quad*8);
      sacc[j] = __builtin_amdgcn_mfma_f32_16x16x32_bf16(aq1, bk1, sacc[j], 0, 0, 0);
    }

    float sv[5][4];
    #pragma unroll
    for (int j = 0; j < 5; ++j){
      int kk = j*16 + ml;
      #pragma unroll
      for (int r = 0; r < 4; ++r)
        sv[j][r] = (kk < 65) ? (sacc[j][r]*0.125f + bb[j][r]) : -1e9f;
    }
    #pragma unroll
    for (int r = 0; r < 4; ++r){
      float mx = sv[0][r];
      #pragma unroll
      for (int j = 1; j < 5; ++j) mx = fmaxf(mx, sv[j][r]);
      #pragma unroll
      for (int o = 1; o < 16; o <<= 1) mx = fmaxf(mx, __shfl_xor(mx, o, 64));
      float sm = 0.f;
      #pragma unroll
      for (int j = 0; j < 5; ++j){ float e = __expf(sv[j][r] - mx); sv[j][r] = e; sm += e; }
      #pragma unroll
      for (int o = 1; o < 16; o <<= 1) sm += __shfl_xor(sm, o, 64);
      float inv = 1.0f / sm;
      #pragma unroll
      for (int j = 0; j < 5; ++j) sv[j][r] *= inv;
    }
    #pragma unroll
    for (int j = 0; j < 5; ++j){
      int kk = j*16 + ml;
      #pragma unroll
      for (int r = 0; r < 4; ++r)
        P_s[(w*16 + quad*4 + r)*104 + kk] = f2b(sv[j][r]);
    }
    __syncthreads();

    f32x4 oacc[4];
    #pragma unroll
    for (int j = 0; j < 4; ++j) oacc[j] = zero4;
    #pragma unroll
    for (int s = 0; s < 3; ++s){
      s16x8 ap = *(const s16x8*)(P_s + (w*16 + ml)*104 + s*32 + quad*8);
      #pragma unroll
      for (int j = 0; j < 4; ++j){
        s16x8 bv = *(const s16x8*)(vT_s + (j*16 + ml)*104 + s*32 + quad*8);
        oacc[j] = __builtin_amdgcn_mfma_f32_16x16x32_bf16(ap, bv, oacc[j], 0, 0, 0);
      }
    }
    #pragma unroll
    for (int j = 0; j < 4; ++j){
      int d = j*16 + ml;
      #pragma unroll
      for (int r = 0; r < 4; ++r){
        int l = w*16 + quad*4 + r;
        AO[(yrow0 + l)*512 + h*64 + d] = f2b(oacc[j][r]);
      }
    }
  }
}

// ---------------------------------------------------------------------------
extern "C" void kernel_launch(void* const* d_in, const int* in_sizes, int n_in,
                              void* d_out, int out_size, void* d_ws, size_t ws_size,
                              hipStream_t stream)
{
  const void* x_raw     = d_in[0];
  const unsigned char* mask = (const unsigned char*)d_in[1];
  const void* edge_raw  = d_in[2];
  const void* qkvw_raw  = d_in[3];
  const void* qkvb_raw  = d_in[4];
  const void* projw_raw = d_in[5];
  const void* projb_raw = d_in[6];

  // workspace layout (~343 MB of the 512 MiB provided)
  char* ws = (char*)d_ws;
  size_t off = 0;
  int*  flagm  = (int*)ws;
  int*  flagdt = (int*)(ws + 4);         off += 1024;
  u16*  XC  = (u16*)(ws + off);          off += (size_t)33554432*2;        // 64 MB
  u16*  EB  = (u16*)(ws + off);          off += (size_t)NEDGE*2;           // ~2 MB (fused bias)
  u16*  WT  = (u16*)(ws + off);          off += (size_t)1536*512*2;        // 1.5 MB
  u16*  PT  = (u16*)(ws + off);          off += (size_t)512*512*2;         // 0.5 MB
  u16*  QB  = (u16*)(ws + off);          off += 4096;                      // 1536 bf16
  u16*  PB  = (u16*)(ws + off);          off += 4096;                      // 512 bf16
  u16*  BM  = (u16*)(ws + off);          off += (size_t)1024*512*2;        // 1 MB
  u16*  KVB = (u16*)(ws + off);          off += (size_t)1024*1024*2;       // 2 MB
  u16*  Y   = (u16*)(ws + off);          off += (size_t)MTOT*1536*2;       // 192 MB
  u16*  AO  = (u16*)(ws + off);          off += (size_t)MTOT*512*2;        // 64 MB

  detect_dtype_kernel<<<dim3(1), dim3(128), 0, stream>>>((const u16*)x_raw, flagdt);
  detect_mask_kernel<<<dim3(1), dim3(128), 0, stream>>>(mask, flagm);

  convert_kernel<<<dim3(33554432/8/256), dim3(256), 0, stream>>>(x_raw, XC, 33554432, flagdt);
  build_bias_kernel<<<dim3((NEDGE + 255)/256), dim3(256), 0, stream>>>(edge_raw, mask, flagdt, flagm, EB);
  transpose_conv_kernel<<<dim3((512*1536 + 255)/256), dim3(256), 0, stream>>>(qkvw_raw, WT, 512, 1536, flagdt);
  transpose_conv_kernel<<<dim3((512*512  + 255)/256), dim3(256), 0, stream>>>(projw_raw, PT, 512, 512, flagdt);
  convert_kernel<<<dim3(1), dim3(256), 0, stream>>>(qkvb_raw, QB, 1536, flagdt);
  convert_kernel<<<dim3(1), dim3(256), 0, stream>>>(projb_raw, PB, 512, flagdt);

  block_mean_kernel<<<dim3(1024), dim3(256), 0, stream>>>(XC, BM);
  // KVB = block_mean @ qkv_w[:,512:] + qkv_b[512:]
  gemm_bt_kernel<<<dim3(8, 8), dim3(256), 0, stream>>>(BM, WT + 512*512, QB + 512, KVB, 512, 1024, 512, flagdt, 0, 0);

  // QKV projection: Y[65536,1536] = XC @ WT^T + QB
  gemm_bt_kernel<<<dim3(12, MTOT/128), dim3(256), 0, stream>>>(XC, WT, QB, Y, 512, 1536, 512, flagdt, 0, 0);
  // attention: 1024 blocks x 4 head-pairs
  attn_kernel<<<dim3(1024, 4), dim3(256), 0, stream>>>(Y, KVB, EB, AO);
  // final projection straight into d_out (dtype per flagdt)
  gemm_bt_kernel<<<dim3(4, MTOT/128), dim3(256), 0, stream>>>(AO, PT, PB, (u16*)d_out, 512, 512, 512, flagdt, 1, 0);
}

// Round 6
// 559.047 us; speedup vs baseline: 1.0390x; 1.0390x over previous
//
#include <hip/hip_runtime.h>
#include <hip/hip_bf16.h>
#include <math.h>

typedef unsigned short u16;
typedef __attribute__((ext_vector_type(8))) short s16x8;   // 8 bf16 (4 VGPRs)
typedef __attribute__((ext_vector_type(4))) float f32x4;   // MFMA 16x16 accumulator

#define NB_ 256
#define L_  64
#define KK_ 65
#define C_  512
#define H_  8
#define NEDGE (256*64*65)             // 1,064,960
#define MTOT  65536                   // total rows = B * NB * L

__device__ __forceinline__ float b2f(u16 u){
  union { unsigned int i; float f; } x; x.i = ((unsigned int)u) << 16; return x.f;
}
__device__ __forceinline__ u16 f2b(float f){
  union { float f; unsigned int i; } x; x.f = f;
  return (u16)((x.i + 0x7FFFu + ((x.i >> 16) & 1u)) >> 16);  // RNE
}

// async global->LDS, 16B per lane. LDS dest: wave-uniform base + lane*16.
__device__ __forceinline__ void gload_lds16(const u16* g, u16* l){
  __builtin_amdgcn_global_load_lds(
      (const __attribute__((address_space(1))) unsigned int*)g,
      (__attribute__((address_space(3))) unsigned int*)l,
      16, 0, 0);
}

// ---------------------------------------------------------------------------
// Input dtype detector. flagdt: 1 = f32 inputs, 0 = bf16.
// ---------------------------------------------------------------------------
__global__ void detect_dtype_kernel(const u16* __restrict__ x, int* __restrict__ flagdt){
  __shared__ int cnt;
  if (threadIdx.x == 0) cnt = 0;
  __syncthreads();
  u16 v = x[(size_t)threadIdx.x * 2 * 1001];   // even indices, spread out
  int e = (v >> 7) & 0xFF;                     // bf16 exponent field
  if (e >= 141) atomicAdd(&cnt, 1);            // |v| >= 2^14 or NaN/Inf
  __syncthreads();
  if (threadIdx.x == 0) *flagdt = (cnt >= 8) ? 1 : 0;
}

// ---------------------------------------------------------------------------
// Mask dtype detector: attn_mask[:, :, 64] is always True under the true
// element width; wrong widths read random data and fail w.p. ~1.
// ---------------------------------------------------------------------------
__global__ void detect_mask_kernel(const unsigned char* __restrict__ m, int* __restrict__ flag){
  __shared__ int ok1, ok2, ok4;
  if (threadIdx.x == 0){ ok1 = 1; ok2 = 1; ok4 = 1; }
  __syncthreads();
  size_t e = (size_t)threadIdx.x * 65 + 64;   // rows 0..127 (n=0,1), col 64
  if (((const unsigned char*)m)[e] == 0)  atomicAnd(&ok1, 0);
  if (((const unsigned short*)m)[e] == 0) atomicAnd(&ok2, 0);
  if (((const unsigned int*)m)[e] == 0u)  atomicAnd(&ok4, 0);
  __syncthreads();
  if (threadIdx.x == 0){
    int f = 4;
    if (ok2) f = 2;
    if (ok1) f = 1;
    *flag = f;
  }
}

// ---------------------------------------------------------------------------
// Canonicalize a float tensor to bf16 (n must be a multiple of 8)
// ---------------------------------------------------------------------------
__global__ void convert_kernel(const void* __restrict__ src, u16* __restrict__ dst,
                               long n, const int* __restrict__ flagdt){
  long i = ((long)blockIdx.x * 256 + threadIdx.x) * 8;
  if (i >= n) return;
  if (*flagdt){
    const float* s = (const float*)src + i;
    u16 o[8];
    #pragma unroll
    for (int j = 0; j < 8; ++j) o[j] = f2b(s[j]);
    *(s16x8*)(dst + i) = *(const s16x8*)o;
  } else {
    *(s16x8*)(dst + i) = *(const s16x8*)((const u16*)src + i);
  }
}

// ---------------------------------------------------------------------------
// Fused score-bias precompute: dst[i] for i = (nb*64 + l)*65 + kk:
//   !mask          -> -1e9
//   kk==64 || kk==l -> 1.0
//   else            -> edge_feats[i][3]
// ---------------------------------------------------------------------------
__global__ void build_bias_kernel(const void* __restrict__ edge,
                                  const unsigned char* __restrict__ mask,
                                  const int* __restrict__ flagdt,
                                  const int* __restrict__ flagm,
                                  u16* __restrict__ dst){
  long i = (long)blockIdx.x * 256 + threadIdx.x;
  if (i >= NEDGE) return;
  int kk = (int)(i % 65);
  long rowi = i / 65;                 // nb*64 + l
  int l = (int)(rowi & 63);
  int fm = *flagm;
  bool mt;
  if (fm == 1)      mt = mask[i] != 0;
  else if (fm == 2) mt = ((const unsigned short*)mask)[i] != 0;
  else              mt = ((const unsigned int*)mask)[i]   != 0u;
  float v;
  if (!mt)                      v = -1e9f;
  else if (kk == 64 || kk == l) v = 1.0f;
  else v = (*flagdt) ? ((const float*)edge)[i*4 + 3] : b2f(((const u16*)edge)[i*4 + 3]);
  dst[i] = f2b(v);
}

// transpose + canonicalize weight matrices (small)
__global__ void transpose_conv_kernel(const void* __restrict__ in, u16* __restrict__ out,
                                      int R, int Cc, const int* __restrict__ flagdt){
  long i = (long)blockIdx.x * 256 + threadIdx.x;
  if (i < (long)R * Cc){
    int r = (int)(i / Cc), c = (int)(i % Cc);
    u16 v = (*flagdt) ? f2b(((const float*)in)[i]) : ((const u16*)in)[i];
    out[(long)c * R + r] = v;
  }
}

// ---------------------------------------------------------------------------
// Per-block mean over L=64 rows -> BM[1024][512]   (reads canonical bf16 X)
// ---------------------------------------------------------------------------
__global__ __launch_bounds__(256) void block_mean_kernel(const u16* __restrict__ x, u16* __restrict__ bm){
  int blk = blockIdx.x;
  const u16* xp = x + (long)blk * 64 * 512;
  for (int c = threadIdx.x; c < 512; c += 256){
    float s = 0.f;
    #pragma unroll
    for (int l = 0; l < 64; ++l) s += b2f(xp[l*512 + c]);
    bm[(long)blk * 512 + c] = f2b(s * 0.015625f);
  }
}

// ---------------------------------------------------------------------------
// GEMM: C[M,N] = A[M,K] @ BT[N,K]^T + bias[n]
// 128x128 tile, BK=64 (two 32-wide halves), 4 waves, 16x16x32 bf16 MFMA.
// ROUND-4 VERIFIED STRUCTURE (153 us QKV) — the round-5 2-phase counted-
// vmcnt pipeline regressed (compiler re-inserts vmcnt(0) before aliasing
// ds_reads; guide m131-m141) and is reverted.
// Each 32-wide half uses the m97-style layout (global-source XOR swizzle +
// linear LDS dest via global_load_lds w=16) at base offsets 0 / 8 KB.
// One barrier pair per 64-wide K-step. LDS 32 KB. Kdim % 64 == 0.
// out_mode=1: consult *flagdt; if set, write f32 at Cmat (cast) with the
// given row offset in ELEMENTS of the output dtype (row_off rows of ldc).
// ---------------------------------------------------------------------------
__global__ __launch_bounds__(256) void gemm_bt_kernel(
    const u16* __restrict__ A, const u16* __restrict__ BT,
    const u16* __restrict__ bias, u16* __restrict__ Cmat,
    int lda, int ldc, int Kdim, const int* __restrict__ flagdt, int out_mode,
    long row_off)
{
  __shared__ __align__(16) u16 As[2*128*32];   // 16 KB: halves at 0 / 4096 elem
  __shared__ __align__(16) u16 Bs[2*128*32];
  const int t = threadIdx.x;
  const int lane = t & 63;
  const int w = t >> 6;
  const int wm = w & 1, wn = w >> 1;
  const int quad = lane >> 4;
  const int ml = lane & 15;

  // XCD-aware bijective swizzle (all grids used have nwg % 8 == 0)
  const int nwg  = gridDim.x * gridDim.y;
  const int orig = blockIdx.y * gridDim.x + blockIdx.x;
  int lid = orig;
  if ((nwg & 7) == 0) lid = (orig & 7) * (nwg >> 3) + (orig >> 3);
  const int bx = lid % gridDim.x;
  const int by = lid / gridDim.x;
  const long colbase = (long)bx * 128;
  const long rowbase = (long)by * 128;
  const int of = out_mode ? *flagdt : 0;

  const f32x4 zero4 = {0.f, 0.f, 0.f, 0.f};
  f32x4 acc[4][4];
  #pragma unroll
  for (int i = 0; i < 4; ++i)
    #pragma unroll
    for (int j = 0; j < 4; ++j) acc[i][j] = zero4;

  // source-address swizzle: thread t's LDS slot byte offset is t*16 (batch0)
  // / 4096+t*16 (batch1); its global source is row r, 16B-chunk g = s ^ ((r>>1)&3).
  const int c0 = t,       r0 = c0 >> 2, s0 = c0 & 3, g0 = s0 ^ ((r0 >> 1) & 3);
  const int c1 = t + 256, r1 = c1 >> 2, s1 = c1 & 3, g1 = s1 ^ ((r1 >> 1) & 3);
  const u16* Arow0 = A + (rowbase + r0) * (long)lda + g0*8;
  const u16* Arow1 = A + (rowbase + r1) * (long)lda + g1*8;
  const u16* Brow0 = BT + (colbase + r0) * (long)Kdim + g0*8;
  const u16* Brow1 = BT + (colbase + r1) * (long)Kdim + g1*8;

  for (int k0 = 0; k0 < Kdim; k0 += 64){
    __syncthreads();                     // all fragment reads of prev tile done
    // half 0 (k0..k0+31) at elem base 0; half 1 (k0+32..k0+63) at elem base 4096
    gload_lds16(Arow0 + k0,      As + w*512);
    gload_lds16(Arow1 + k0,      As + 2048 + w*512);
    gload_lds16(Arow0 + k0 + 32, As + 4096 + w*512);
    gload_lds16(Arow1 + k0 + 32, As + 4096 + 2048 + w*512);
    gload_lds16(Brow0 + k0,      Bs + w*512);
    gload_lds16(Brow1 + k0,      Bs + 2048 + w*512);
    gload_lds16(Brow0 + k0 + 32, Bs + 4096 + w*512);
    gload_lds16(Brow1 + k0 + 32, Bs + 4096 + 2048 + w*512);
    __syncthreads();                     // drains vmcnt -> both halves ready
    #pragma unroll
    for (int hb = 0; hb < 2; ++hb){
      const u16* Ab = As + hb*4096;
      const u16* Bb = Bs + hb*4096;
      s16x8 af[4], bfr[4];
      #pragma unroll
      for (int i = 0; i < 4; ++i){
        int m = wm*64 + i*16 + ml;
        af[i]  = *(const s16x8*)(Ab + m*32 + ((quad ^ ((m>>1)&3)))*8);
        int n = wn*64 + i*16 + ml;
        bfr[i] = *(const s16x8*)(Bb + n*32 + ((quad ^ ((n>>1)&3)))*8);
      }
      #pragma unroll
      for (int i = 0; i < 4; ++i)
        #pragma unroll
        for (int j = 0; j < 4; ++j)
          acc[i][j] = __builtin_amdgcn_mfma_f32_16x16x32_bf16(af[i], bfr[j], acc[i][j], 0, 0, 0);
    }
  }

  // epilogue: C/D layout col=lane&15, row=quad*4+reg
  #pragma unroll
  for (int j = 0; j < 4; ++j){
    long col = colbase + wn*64 + j*16 + ml;
    float bv = b2f(bias[col]);
    #pragma unroll
    for (int i = 0; i < 4; ++i){
      long row = row_off + rowbase + wm*64 + i*16 + quad*4;
      if (of){
        float* Cf = (float*)Cmat;
        #pragma unroll
        for (int r = 0; r < 4; ++r)
          Cf[(row + r) * (long)ldc + col] = acc[i][j][r] + bv;
      } else {
        #pragma unroll
        for (int r = 0; r < 4; ++r)
          Cmat[(row + r) * (long)ldc + col] = f2b(acc[i][j][r] + bv);
      }
    }
  }
}

// ---------------------------------------------------------------------------
// Attention: one WG per (block, head-QUAD), grid 1024x2. Four heads run
// sequentially; while head h computes softmax+PV, head h+1's K/V rows are
// prefetched into registers (T14 async-stage: issue-early / write-late).
// The ds_write of head h+1 happens after a barrier that closes head h's
// PV ds_reads, so the single LDS buffer is safely reused.
// Bias regs + LDS pad zero-fills amortize 4x. LDS 37.25 KB -> 4 WG/CU.
// ---------------------------------------------------------------------------
__global__ __launch_bounds__(256, 4) void attn_kernel(
    const u16* __restrict__ Y, const u16* __restrict__ kvb,
    const u16* __restrict__ biasb, u16* __restrict__ AO)
{
  __shared__ __align__(16) u16 k_s [80*72];
  __shared__ __align__(16) u16 vT_s[64*104];
  __shared__ __align__(16) u16 P_s [64*104];

  const int t = threadIdx.x;
  const int lane = t & 63;
  const int w = t >> 6;
  const int quad = lane >> 4;
  const int ml = lane & 15;

  // XCD swizzle (bijective on 0..2047): both head-quads of a block adjacent
  const int orig = blockIdx.y * gridDim.x + blockIdx.x;   // 0..2047
  const int lid  = (orig & 7) * 256 + (orig >> 3);
  const int blk  = lid >> 1;
  const int hq   = lid & 1;          // head quad: heads hq*4 .. hq*4+3
  const int nb = blk & (NB_ - 1);
  const long yrow0 = (long)blk * 64;

  // head-independent score bias -> registers (reused for all 4 heads)
  float bb[5][4];
  #pragma unroll
  for (int j = 0; j < 5; ++j){
    int kk = j*16 + ml;
    #pragma unroll
    for (int r = 0; r < 4; ++r){
      int l = w*16 + quad*4 + r;
      bb[j][r] = (kk < 65) ? b2f(biasb[((long)nb*64 + l)*65 + kk]) : 0.f;
    }
  }

  // pad zero-fills (persist across all heads)
  for (int i = t; i < 64*31; i += 256){ int d = i/31, c = 65 + (i%31); vT_s[d*104 + c] = 0; }
  for (int i = t; i < 64*16; i += 256){ int l = i>>4,  c = 80 + (i&15); P_s[l*104 + c] = 0; }
  for (int i = t; i < 15*72; i += 256){ k_s[65*72 + i] = 0; }

  // per-thread staging coordinates (two Y-row chunks per thread)
  const int kk0 = t >> 3,  c8 = t & 7;       // kk0 in 0..31
  const int kk1 = kk0 + 32;                  // 32..63
  const u16* yb0 = Y + (yrow0 + kk0)*1536;
  const u16* yb1 = Y + (yrow0 + kk1)*1536;
  const u16* kvbase = kvb + (long)blk * 1024;

  const f32x4 zero4 = {0.f, 0.f, 0.f, 0.f};
  s16x8 kr0, vr0, kr1, vr1;                  // rolling prefetch registers

  for (int hh = 0; hh < 4; ++hh){
    const int h = hq*4 + hh;

    if (hh == 0){
      // direct stage of head 0 (latency exposed once per WG)
      for (int c = t; c < 520; c += 256){
        int kk = c >> 3, cc = c & 7;
        const u16 *srck, *srcv;
        if (kk < 64){
          const u16* base = Y + (yrow0 + kk)*1536;
          srck = base + 512  + h*64 + cc*8;
          srcv = base + 1024 + h*64 + cc*8;
        } else {
          srck = kvbase + h*64 + cc*8;
          srcv = kvbase + 512 + h*64 + cc*8;
        }
        *(s16x8*)(k_s + kk*72 + cc*8) = *(const s16x8*)srck;
        s16x8 vv = *(const s16x8*)srcv;
        #pragma unroll
        for (int j = 0; j < 8; ++j){
          int jj = (j + cc) & 7;        // bank-rotate scatter: 16-way -> 2-way
          vT_s[(cc*8 + jj)*104 + kk] = (u16)vv[jj];
        }
      }
    } else {
      __syncthreads();                  // close prev head's PV ds_reads
      // write prefetched K/V regs (Y rows 0..63)
      *(s16x8*)(k_s + kk0*72 + c8*8) = kr0;
      *(s16x8*)(k_s + kk1*72 + c8*8) = kr1;
      #pragma unroll
      for (int j = 0; j < 8; ++j){
        int jj = (j + c8) & 7;
        vT_s[(c8*8 + jj)*104 + kk0] = (u16)vr0[jj];
        vT_s[(c8*8 + jj)*104 + kk1] = (u16)vr1[jj];
      }
      // kk=64 row from kvb (tiny, L2-resident): threads 0..7
      if (t < 8){
        *(s16x8*)(k_s + 64*72 + t*8) = *(const s16x8*)(kvbase + h*64 + t*8);
        s16x8 vv = *(const s16x8*)(kvbase + 512 + h*64 + t*8);
        #pragma unroll
        for (int j = 0; j < 8; ++j){
          int jj = (j + t) & 7;
          vT_s[(t*8 + jj)*104 + 64] = (u16)vv[jj];
        }
      }
    }
    __syncthreads();

    // Q fragments straight to registers
    const u16* qrow = Y + (yrow0 + w*16 + ml)*1536 + h*64 + quad*8;
    s16x8 aq0 = *(const s16x8*)(qrow);
    s16x8 aq1 = *(const s16x8*)(qrow + 32);

    f32x4 sacc[5];
    #pragma unroll
    for (int j = 0; j < 5; ++j) sacc[j] = zero4;
    #pragma unroll
    for (int j = 0; j < 5; ++j){
      s16x8 bk0 = *(const s16x8*)(k_s + (j*16 + ml)*72 + quad*8);
      sacc[j] = __builtin_amdgcn_mfma_f32_16x16x32_bf16(aq0, bk0, sacc[j], 0, 0, 0);
      s16x8 bk1 = *(const s16x8*)(k_s + (j*16 + ml)*72 + 32 + quad*8);
      sacc[j] = __builtin_amdgcn_mfma_f32_16x16x32_bf16(aq1, bk1, sacc[j], 0, 0, 0);
    }

    // prefetch next head's K/V into registers (latency hides under
    // softmax + P-write + PV below)
    if (hh < 3){
      const int hn = h + 1;
      kr0 = *(const s16x8*)(yb0 + 512  + hn*64 + c8*8);
      vr0 = *(const s16x8*)(yb0 + 1024 + hn*64 + c8*8);
      kr1 = *(const s16x8*)(yb1 + 512  + hn*64 + c8*8);
      vr1 = *(const s16x8*)(yb1 + 1024 + hn*64 + c8*8);
    }

    float sv[5][4];
    #pragma unroll
    for (int j = 0; j < 5; ++j){
      int kk = j*16 + ml;
      #pragma unroll
      for (int r = 0; r < 4; ++r)
        sv[j][r] = (kk < 65) ? (sacc[j][r]*0.125f + bb[j][r]) : -1e9f;
    }
    #pragma unroll
    for (int r = 0; r < 4; ++r){
      float mx = sv[0][r];
      #pragma unroll
      for (int j = 1; j < 5; ++j) mx = fmaxf(mx, sv[j][r]);
      #pragma unroll
      for (int o = 1; o < 16; o <<= 1) mx = fmaxf(mx, __shfl_xor(mx, o, 64));
      float sm = 0.f;
      #pragma unroll
      for (int j = 0; j < 5; ++j){ float e = __expf(sv[j][r] - mx); sv[j][r] = e; sm += e; }
      #pragma unroll
      for (int o = 1; o < 16; o <<= 1) sm += __shfl_xor(sm, o, 64);
      float inv = 1.0f / sm;
      #pragma unroll
      for (int j = 0; j < 5; ++j) sv[j][r] *= inv;
    }
    #pragma unroll
    for (int j = 0; j < 5; ++j){
      int kk = j*16 + ml;
      #pragma unroll
      for (int r = 0; r < 4; ++r)
        P_s[(w*16 + quad*4 + r)*104 + kk] = f2b(sv[j][r]);
    }
    __syncthreads();

    f32x4 oacc[4];
    #pragma unroll
    for (int j = 0; j < 4; ++j) oacc[j] = zero4;
    #pragma unroll
    for (int s = 0; s < 3; ++s){
      s16x8 ap = *(const s16x8*)(P_s + (w*16 + ml)*104 + s*32 + quad*8);
      #pragma unroll
      for (int j = 0; j < 4; ++j){
        s16x8 bv = *(const s16x8*)(vT_s + (j*16 + ml)*104 + s*32 + quad*8);
        oacc[j] = __builtin_amdgcn_mfma_f32_16x16x32_bf16(ap, bv, oacc[j], 0, 0, 0);
      }
    }
    #pragma unroll
    for (int j = 0; j < 4; ++j){
      int d = j*16 + ml;
      #pragma unroll
      for (int r = 0; r < 4; ++r){
        int l = w*16 + quad*4 + r;
        AO[(yrow0 + l)*512 + h*64 + d] = f2b(oacc[j][r]);
      }
    }
  }
}

// ---------------------------------------------------------------------------
extern "C" void kernel_launch(void* const* d_in, const int* in_sizes, int n_in,
                              void* d_out, int out_size, void* d_ws, size_t ws_size,
                              hipStream_t stream)
{
  const void* x_raw     = d_in[0];
  const unsigned char* mask = (const unsigned char*)d_in[1];
  const void* edge_raw  = d_in[2];
  const void* qkvw_raw  = d_in[3];
  const void* qkvb_raw  = d_in[4];
  const void* projw_raw = d_in[5];
  const void* projb_raw = d_in[6];

  // workspace layout (~343 MB of the 512 MiB provided)
  char* ws = (char*)d_ws;
  size_t off = 0;
  int*  flagm  = (int*)ws;
  int*  flagdt = (int*)(ws + 4);         off += 1024;
  u16*  XC  = (u16*)(ws + off);          off += (size_t)33554432*2;        // 64 MB
  u16*  EB  = (u16*)(ws + off);          off += (size_t)NEDGE*2;           // ~2 MB (fused bias)
  u16*  WT  = (u16*)(ws + off);          off += (size_t)1536*512*2;        // 1.5 MB
  u16*  PT  = (u16*)(ws + off);          off += (size_t)512*512*2;         // 0.5 MB
  u16*  QB  = (u16*)(ws + off);          off += 4096;                      // 1536 bf16
  u16*  PB  = (u16*)(ws + off);          off += 4096;                      // 512 bf16
  u16*  BM  = (u16*)(ws + off);          off += (size_t)1024*512*2;        // 1 MB
  u16*  KVB = (u16*)(ws + off);          off += (size_t)1024*1024*2;       // 2 MB
  u16*  Y   = (u16*)(ws + off);          off += (size_t)MTOT*1536*2;       // 192 MB
  u16*  AO  = (u16*)(ws + off);          off += (size_t)MTOT*512*2;        // 64 MB

  detect_dtype_kernel<<<dim3(1), dim3(128), 0, stream>>>((const u16*)x_raw, flagdt);
  detect_mask_kernel<<<dim3(1), dim3(128), 0, stream>>>(mask, flagm);

  convert_kernel<<<dim3(33554432/8/256), dim3(256), 0, stream>>>(x_raw, XC, 33554432, flagdt);
  build_bias_kernel<<<dim3((NEDGE + 255)/256), dim3(256), 0, stream>>>(edge_raw, mask, flagdt, flagm, EB);
  transpose_conv_kernel<<<dim3((512*1536 + 255)/256), dim3(256), 0, stream>>>(qkvw_raw, WT, 512, 1536, flagdt);
  transpose_conv_kernel<<<dim3((512*512  + 255)/256), dim3(256), 0, stream>>>(projw_raw, PT, 512, 512, flagdt);
  convert_kernel<<<dim3(1), dim3(256), 0, stream>>>(qkvb_raw, QB, 1536, flagdt);
  convert_kernel<<<dim3(1), dim3(256), 0, stream>>>(projb_raw, PB, 512, flagdt);

  block_mean_kernel<<<dim3(1024), dim3(256), 0, stream>>>(XC, BM);
  // KVB = block_mean @ qkv_w[:,512:] + qkv_b[512:]
  gemm_bt_kernel<<<dim3(8, 8), dim3(256), 0, stream>>>(BM, WT + 512*512, QB + 512, KVB, 512, 1024, 512, flagdt, 0, 0);

  // QKV projection: Y[65536,1536] = XC @ WT^T + QB
  gemm_bt_kernel<<<dim3(12, MTOT/128), dim3(256), 0, stream>>>(XC, WT, QB, Y, 512, 1536, 512, flagdt, 0, 0);
  // attention: 1024 blocks x 2 head-quads
  attn_kernel<<<dim3(1024, 2), dim3(256), 0, stream>>>(Y, KVB, EB, AO);
  // final projection straight into d_out (dtype per flagdt)
  gemm_bt_kernel<<<dim3(4, MTOT/128), dim3(256), 0, stream>>>(AO, PT, PB, (u16*)d_out, 512, 512, 512, flagdt, 1, 0);
}